// Round 7
// baseline (52.951 us; speedup 1.0000x reference)
//
#include <hip/hip_runtime.h>
#include <hip/hip_bf16.h>

typedef __attribute__((ext_vector_type(8))) short short8;
typedef __attribute__((ext_vector_type(4))) float f32x4;

#define NROWS 8192
#define DCOLS 256
#define MARGIN 0.5f
#define NT 32          // 8192/256 supertiles per dim
#define NBLK 528       // NT*(NT+1)/2 upper-triangle tiles

// Fragment-major layout eT (4 MB total):
//   fragment f = rowtile*8 + kt   (rowtile = global_row/16, kt = k/32), 1 KB each
//   within fragment, lane chunk (lr = row&15, hk = k_grp) at byte (lr*4 + hk)*16,
//   holding rows rowtile*16+lr, k = kt*32 + hk*8 .. +7  (bf16x8 = 16 B)
// This is exactly the mfma_f32_16x16x32_bf16 A/B operand layout (lane l -> lr=l&15,
// hk=l>>4), so both operands load as one dense 1 KB read per fragment.

// --- Kernel 1: L2-normalize rows fp32 -> bf16, write fragment-major eT ---
// 2 rows per wave (32 lanes/row, 8 cols/lane). Stores are 64B-line-complete.
__global__ __launch_bounds__(256) void norm_kernel(const float* __restrict__ x,
                                                   unsigned short* __restrict__ eT) {
    const int t = threadIdx.x;
    const int l = t & 63;
    const int c = l & 31;                       // col-group of 8
    const int row = blockIdx.x * 8 + (t >> 6) * 2 + (l >> 5);

    const float4 v0 = *reinterpret_cast<const float4*>(&x[row * DCOLS + c * 8]);
    const float4 v1 = *reinterpret_cast<const float4*>(&x[row * DCOLS + c * 8 + 4]);
    float ss = v0.x * v0.x + v0.y * v0.y + v0.z * v0.z + v0.w * v0.w
             + v1.x * v1.x + v1.y * v1.y + v1.z * v1.z + v1.w * v1.w;
#pragma unroll
    for (int off = 16; off >= 1; off >>= 1) ss += __shfl_xor(ss, off, 32);
    const float inv = 1.0f / fmaxf(sqrtf(ss), 1e-12f);

    const float f[8] = {v0.x, v0.y, v0.z, v0.w, v1.x, v1.y, v1.z, v1.w};
    short8 o;
#pragma unroll
    for (int i = 0; i < 8; ++i) {
        __hip_bfloat16 h = __float2bfloat16(f[i] * inv);
        o[i] = *reinterpret_cast<const short*>(&h);
    }
    // frag (row>>4, kt=c>>2), chunk (row&15, hk=c&3)
    const size_t boff = (size_t)(row >> 4) * 8192 + (size_t)(c >> 2) * 1024
                      + (size_t)(row & 15) * 64 + (size_t)(c & 3) * 16;
    *reinterpret_cast<short8*>((char*)eT + boff) = o;
}

// --- Kernel 2: 256x256 sim supertiles, compact triangular grid, NO LDS, NO
// barriers. Each wave owns a 128x64 sub-tile (acc[8][4] of 16x16x32 bf16 MFMA);
// fragments loaded directly from fragment-major eT (L2-resident, coalesced 1KB
// per load; A-frags shared by the 4 same-wm waves via L1). Compiler pipelines
// the fully-unrolled 8 K-tile loop with counted vmcnt (its proven strength).
__global__ __launch_bounds__(512, 2) void tile_kernel(const unsigned short* __restrict__ eT,
                                                      float* __restrict__ part) {
    // XCD-aware bijective swizzle (NBLK = 528 = 8*66)
    const int orig = blockIdx.x;
    const int t0 = (orig & 7) * 66 + (orig >> 3);
    // decode t0 -> (bi,bj), bi<=bj, over NT x NT upper triangle
    int bi = (int)((65.0 - sqrt(4225.0 - 8.0 * (double)t0)) * 0.5);
    if (bi < 0) bi = 0;
    if (bi > NT - 1) bi = NT - 1;
#define CUM(b) (((b) * (65 - (b))) >> 1)
    while (bi + 1 <= NT - 1 && CUM(bi + 1) <= t0) ++bi;
    while (bi > 0 && CUM(bi) > t0) --bi;
    const int bj = bi + (t0 - CUM(bi));
#undef CUM

    __shared__ float red[8];

    const int t = threadIdx.x;
    const int l = t & 63;
    const int w = t >> 6;        // 0..7
    const int wm = w >> 2;       // wave M 0..1  (wave tile 128 rows)
    const int wn = w & 3;        // wave N 0..3  (wave tile 64 cols)
    const int lr = l & 15;
    const int hk = l >> 4;
    const int perm = (lr * 4 + hk) * 16;   // this lane's chunk offset in a frag

    const char* baseA = (const char*)eT + (size_t)(bi * 16 + wm * 8) * 8192 + perm;
    const char* baseB = (const char*)eT + (size_t)(bj * 16 + wn * 4) * 8192 + perm;

    f32x4 acc[8][4];
#pragma unroll
    for (int m = 0; m < 8; ++m)
#pragma unroll
        for (int n = 0; n < 4; ++n)
            acc[m][n] = (f32x4){0.f, 0.f, 0.f, 0.f};

#pragma unroll
    for (int kt = 0; kt < 8; ++kt) {
        short8 af[8], bf[4];
#pragma unroll
        for (int m = 0; m < 8; ++m)
            af[m] = *reinterpret_cast<const short8*>(baseA + m * 8192 + kt * 1024);
#pragma unroll
        for (int n = 0; n < 4; ++n)
            bf[n] = *reinterpret_cast<const short8*>(baseB + n * 8192 + kt * 1024);
        __builtin_amdgcn_s_setprio(1);
#pragma unroll
        for (int m = 0; m < 8; ++m)
#pragma unroll
            for (int n = 0; n < 4; ++n)
                acc[m][n] = __builtin_amdgcn_mfma_f32_16x16x32_bf16(af[m], bf[n], acc[m][n], 0, 0, 0);
        __builtin_amdgcn_s_setprio(0);
    }

    // --- epilogue: relu(sim - margin), strict upper-triangle mask, reduce ---
    // C/D layout (m89-verified): col = lane&15, row = (lane>>4)*4 + reg.
    const int gi0 = bi * 256 + wm * 128;
    const int gj0 = bj * 256 + wn * 64;
    float local = 0.0f;
#pragma unroll
    for (int m = 0; m < 8; ++m) {
#pragma unroll
        for (int n = 0; n < 4; ++n) {
#pragma unroll
            for (int r = 0; r < 4; ++r) {
                const int gi = gi0 + m * 16 + hk * 4 + r;
                const int gj = gj0 + n * 16 + lr;
                const float v = acc[m][n][r] - MARGIN;
                local += (gi < gj) ? fmaxf(v, 0.0f) : 0.0f;
            }
        }
    }
#pragma unroll
    for (int off = 32; off >= 1; off >>= 1) local += __shfl_down(local, off);
    if (l == 0) red[w] = local;
    __syncthreads();
    if (t == 0) {
        float s = 0.0f;
#pragma unroll
        for (int i = 0; i < 8; ++i) s += red[i];
        part[orig] = s;
    }
}

// --- Kernel 3: reduce NBLK partials, finalize ---
__global__ __launch_bounds__(512) void fin_kernel(const float* __restrict__ part,
                                                  float* __restrict__ out) {
    __shared__ float red[8];
    const int t = threadIdx.x;
    float v = part[t] + (t < NBLK - 512 ? part[512 + t] : 0.0f);
#pragma unroll
    for (int off = 32; off >= 1; off >>= 1) v += __shfl_down(v, off);
    if ((t & 63) == 0) red[t >> 6] = v;
    __syncthreads();
    if (t == 0) {
        float s = 0.0f;
#pragma unroll
        for (int i = 0; i < 8; ++i) s += red[i];
        out[0] = s / 33550336.0f;   // n*(n-1)/2 for n=8192
    }
}

extern "C" void kernel_launch(void* const* d_in, const int* in_sizes, int n_in,
                              void* d_out, int out_size, void* d_ws, size_t ws_size,
                              hipStream_t stream) {
    const float* x = (const float*)d_in[0];
    float* out = (float*)d_out;
    unsigned short* eT = (unsigned short*)d_ws;
    float* part = (float*)((char*)d_ws + (size_t)NROWS * DCOLS * 2);

    norm_kernel<<<NROWS / 8, 256, 0, stream>>>(x, eT);
    tile_kernel<<<NBLK, 512, 0, stream>>>(eT, part);
    fin_kernel<<<1, 512, 0, stream>>>(part, out);
}

// Round 8
// 41.227 us; speedup vs baseline: 1.2844x; 1.2844x over previous
//
#include <hip/hip_runtime.h>
#include <hip/hip_bf16.h>

typedef __attribute__((ext_vector_type(8))) short short8;
typedef __attribute__((ext_vector_type(4))) float f32x4;

#define NROWS 8192
#define DCOLS 256
#define MARGIN 0.5f
#define NT 32          // 8192/256 supertiles per dim
#define NBLK 528       // NT*(NT+1)/2 upper-triangle tiles
#define KT 4           // K-tiles of BK=64

// --- Kernel 1: L2-normalize rows fp32 -> bf16, one wave per row ---
__global__ __launch_bounds__(256) void norm_kernel(const float* __restrict__ x,
                                                   unsigned short* __restrict__ e) {
    const int wave = threadIdx.x >> 6;
    const int lane = threadIdx.x & 63;
    const int row = blockIdx.x * 4 + wave;

    const float4 v = *reinterpret_cast<const float4*>(&x[row * DCOLS + lane * 4]);
    float ss = v.x * v.x + v.y * v.y + v.z * v.z + v.w * v.w;
#pragma unroll
    for (int off = 32; off >= 1; off >>= 1) ss += __shfl_down(ss, off);
    ss = __shfl(ss, 0);
    const float inv = 1.0f / fmaxf(sqrtf(ss), 1e-12f);

    __hip_bfloat16 h0 = __float2bfloat16(v.x * inv);
    __hip_bfloat16 h1 = __float2bfloat16(v.y * inv);
    __hip_bfloat16 h2 = __float2bfloat16(v.z * inv);
    __hip_bfloat16 h3 = __float2bfloat16(v.w * inv);
    ushort4 o;
    o.x = *reinterpret_cast<unsigned short*>(&h0);
    o.y = *reinterpret_cast<unsigned short*>(&h1);
    o.z = *reinterpret_cast<unsigned short*>(&h2);
    o.w = *reinterpret_cast<unsigned short*>(&h3);
    *reinterpret_cast<ushort4*>(&e[row * DCOLS + lane * 4]) = o;
}

// Stage one 128x64 bf16 half-tile (16 KB) via global_load_lds width 16.
// Half-tile LDS layout: [128 rows][8 slots x 16B] (128B rows), physical slot =
// logical k-chunk ^ (row&7)  -> hardware-verified 0-conflict reads (R3 run).
// Linear LDS dest (wave-uniform base + lane*16), inverse-swizzled global source
// (rule #21). 2 loads per thread per half-tile.
__device__ __forceinline__ void stage_half(const unsigned short* __restrict__ src,
                                           char* lds_base, int kt, int w, int l) {
#pragma unroll
    for (int i = 0; i < 2; ++i) {
        const int ch  = i * 512 + w * 64 + l;   // 16B chunk id, 0..1023
        const int row = ch >> 3;                // 0..127
        const int sl  = (ch & 7) ^ (row & 7);   // inverse swizzle
        __builtin_amdgcn_global_load_lds(
            (const __attribute__((address_space(1))) void*)(src + row * DCOLS + kt * 64 + sl * 8),
            (__attribute__((address_space(3))) void*)(lds_base + ch * 16), 16, 0, 0);
    }
}

// --- Kernel 2: 256x256 sim supertiles, 8-phase-per-2-K-tiles schedule (m201
// template port). 8 waves (2M x 4N), wave tile 128x64 = acc[8][4] of 16x16x32.
// LDS 128 KB: {A,B} x 2 dbuf x 2 M-half x 16KB. Per phase (t,q):
//   q0: vmcnt(0) [tile t's 8 loads, issued 3-4 phases ago] ; barrier ;
//       stage A(t+1) halves -> dbuf^1 ; ds_read all B frags + A m-pair 0
//   q1: stage B(t+1) halves ; ds_read A m-pair 1
//   q2/q3: ds_read A m-pair only
//   then: lgkmcnt(0); sched_barrier; setprio(1); 16 MFMA; setprio(0); s_barrier
// Loads stay in flight across the q1..q3 barriers (T4); vmcnt never waits on
// recently-issued loads. Staging targets dbuf^1 whose readers finished before
// this tile's q0 barrier -> no overwrite race.
__global__ __launch_bounds__(512, 2) void tile_kernel(const unsigned short* __restrict__ e,
                                                      float* __restrict__ part) {
    // XCD-aware bijective swizzle (NBLK = 528 = 8*66)
    const int orig = blockIdx.x;
    const int t0 = (orig & 7) * 66 + (orig >> 3);
    // decode t0 -> (bi,bj), bi<=bj, over NT x NT upper triangle
    int bi = (int)((65.0 - sqrt(4225.0 - 8.0 * (double)t0)) * 0.5);
    if (bi < 0) bi = 0;
    if (bi > NT - 1) bi = NT - 1;
#define CUM(b) (((b) * (65 - (b))) >> 1)
    while (bi + 1 <= NT - 1 && CUM(bi + 1) <= t0) ++bi;
    while (bi > 0 && CUM(bi) > t0) --bi;
    const int bj = bi + (t0 - CUM(bi));
#undef CUM

    __shared__ char lds[131072];   // A: [dbuf][half] @ (d*2+h)*16384 ; B: +65536
    __shared__ float red[8];

    const int t = threadIdx.x;
    const int l = t & 63;
    const int w = t >> 6;        // 0..7
    const int wm = w >> 2;       // wave M 0..1  (rows wm*128..+127)
    const int wn = w & 3;        // wave N 0..3  (cols wn*64..+63)
    const int lr = l & 15;
    const int hk = l >> 4;

    const unsigned short* eA = e + (size_t)bi * 256 * DCOLS;
    const unsigned short* eB = e + (size_t)bj * 256 * DCOLS;

    f32x4 acc[8][4];
#pragma unroll
    for (int m = 0; m < 8; ++m)
#pragma unroll
        for (int n = 0; n < 4; ++n)
            acc[m][n] = (f32x4){0.f, 0.f, 0.f, 0.f};

    // prologue: stage tile 0 (A halves then B halves) into dbuf 0
    stage_half(eA,       lds + 0 * 16384, 0, w, l);
    stage_half(eA + 128 * DCOLS, lds + 1 * 16384, 0, w, l);
    stage_half(eB,       lds + 65536 + 0 * 16384, 0, w, l);
    stage_half(eB + 128 * DCOLS, lds + 65536 + 1 * 16384, 0, w, l);

    short8 bfr[4][2];   // B fragments, live across the 4 phases of a K-tile

#pragma unroll
    for (int kt = 0; kt < KT; ++kt) {
        const int d = kt & 1;
        const char* Abuf = lds + (size_t)(d * 2 + wm) * 16384;
        const char* Bbuf = lds + 65536 + (size_t)(d * 2 + (wn >> 1)) * 16384;
#pragma unroll
        for (int q = 0; q < 4; ++q) {
            if (q == 0) {
                asm volatile("s_waitcnt vmcnt(0)" ::: "memory");   // tile kt landed
                __builtin_amdgcn_s_barrier();                      // visible to all
                __builtin_amdgcn_sched_barrier(0);
                if (kt + 1 < KT) {   // stage A(kt+1) -> dbuf d^1
                    stage_half(eA,             lds + (size_t)((d ^ 1) * 2 + 0) * 16384, kt + 1, w, l);
                    stage_half(eA + 128 * DCOLS, lds + (size_t)((d ^ 1) * 2 + 1) * 16384, kt + 1, w, l);
                }
                // read all B fragments for this K-tile (kept in regs 4 phases)
#pragma unroll
                for (int n = 0; n < 4; ++n) {
                    const int lrow = (wn & 1) * 64 + n * 16 + lr;
#pragma unroll
                    for (int kk = 0; kk < 2; ++kk)
                        bfr[n][kk] = *reinterpret_cast<const short8*>(
                            Bbuf + lrow * 128 + (((kk * 4 + hk) ^ (lrow & 7)) << 4));
                }
            } else if (q == 1) {
                if (kt + 1 < KT) {   // stage B(kt+1) -> dbuf d^1
                    stage_half(eB,             lds + 65536 + (size_t)((d ^ 1) * 2 + 0) * 16384, kt + 1, w, l);
                    stage_half(eB + 128 * DCOLS, lds + 65536 + (size_t)((d ^ 1) * 2 + 1) * 16384, kt + 1, w, l);
                }
            }
            // A fragments for m-pair q
            short8 afr[2][2];
#pragma unroll
            for (int j = 0; j < 2; ++j) {
                const int lrow = (q * 2 + j) * 16 + lr;
#pragma unroll
                for (int kk = 0; kk < 2; ++kk)
                    afr[j][kk] = *reinterpret_cast<const short8*>(
                        Abuf + lrow * 128 + (((kk * 4 + hk) ^ (lrow & 7)) << 4));
            }
            asm volatile("s_waitcnt lgkmcnt(0)" ::: "memory");
            __builtin_amdgcn_sched_barrier(0);   // rule #18: keep MFMA below
            __builtin_amdgcn_s_setprio(1);
#pragma unroll
            for (int j = 0; j < 2; ++j)
#pragma unroll
                for (int n = 0; n < 4; ++n)
#pragma unroll
                    for (int kk = 0; kk < 2; ++kk)
                        acc[q * 2 + j][n] = __builtin_amdgcn_mfma_f32_16x16x32_bf16(
                            afr[j][kk], bfr[n][kk], acc[q * 2 + j][n], 0, 0, 0);
            __builtin_amdgcn_s_setprio(0);
            __builtin_amdgcn_s_barrier();        // phase lockstep (no vmem drain)
        }
    }

    // --- epilogue: relu(sim - margin), strict upper-triangle mask, reduce ---
    // C/D layout (m89-verified): col = lane&15, row = (lane>>4)*4 + reg.
    const int gi0 = bi * 256 + wm * 128;
    const int gj0 = bj * 256 + wn * 64;
    float local = 0.0f;
#pragma unroll
    for (int m = 0; m < 8; ++m) {
#pragma unroll
        for (int n = 0; n < 4; ++n) {
#pragma unroll
            for (int r = 0; r < 4; ++r) {
                const int gi = gi0 + m * 16 + hk * 4 + r;
                const int gj = gj0 + n * 16 + lr;
                const float v = acc[m][n][r] - MARGIN;
                local += (gi < gj) ? fmaxf(v, 0.0f) : 0.0f;
            }
        }
    }
#pragma unroll
    for (int off = 32; off >= 1; off >>= 1) local += __shfl_down(local, off);
    if (l == 0) red[w] = local;
    __syncthreads();
    if (t == 0) {
        float s = 0.0f;
#pragma unroll
        for (int i = 0; i < 8; ++i) s += red[i];
        part[orig] = s;
    }
}

// --- Kernel 3: reduce NBLK partials, finalize ---
__global__ __launch_bounds__(512) void fin_kernel(const float* __restrict__ part,
                                                  float* __restrict__ out) {
    __shared__ float red[8];
    const int t = threadIdx.x;
    float v = part[t] + (t < NBLK - 512 ? part[512 + t] : 0.0f);
#pragma unroll
    for (int off = 32; off >= 1; off >>= 1) v += __shfl_down(v, off);
    if ((t & 63) == 0) red[t >> 6] = v;
    __syncthreads();
    if (t == 0) {
        float s = 0.0f;
#pragma unroll
        for (int i = 0; i < 8; ++i) s += red[i];
        out[0] = s / 33550336.0f;   // n*(n-1)/2 for n=8192
    }
}

extern "C" void kernel_launch(void* const* d_in, const int* in_sizes, int n_in,
                              void* d_out, int out_size, void* d_ws, size_t ws_size,
                              hipStream_t stream) {
    const float* x = (const float*)d_in[0];
    float* out = (float*)d_out;
    unsigned short* e = (unsigned short*)d_ws;
    float* part = (float*)((char*)d_ws + (size_t)NROWS * DCOLS * 2);

    norm_kernel<<<NROWS / 4, 256, 0, stream>>>(x, e);
    tile_kernel<<<NBLK, 512, 0, stream>>>(e, part);
    fin_kernel<<<1, 512, 0, stream>>>(part, out);
}

// Round 9
// 40.657 us; speedup vs baseline: 1.3024x; 1.0140x over previous
//
#include <hip/hip_runtime.h>
#include <hip/hip_fp16.h>

typedef __attribute__((ext_vector_type(4))) float f32x4;

#define NROWS 8192
#define DCOLS 256
#define MARGIN 0.5f
#define NT 64          // 8192/128 tiles per dim
#define NBLOCKS 544    // sum over rows bi of ceil((64-bi)/4) runs of <=4 j-tiles

// --- Kernel 1: L2-normalize rows fp32 -> fp8 e5m2 (= truncated fp16), row-major.
// 2 rows per wave (32 lanes/row, 8 cols/lane); 8B stores, line-complete.
__global__ __launch_bounds__(256) void norm_kernel(const float* __restrict__ x,
                                                   unsigned char* __restrict__ e) {
    const int t = threadIdx.x;
    const int l = t & 63;
    const int c = l & 31;
    const int row = blockIdx.x * 8 + (t >> 6) * 2 + (l >> 5);

    const float4 v0 = *reinterpret_cast<const float4*>(&x[row * DCOLS + c * 8]);
    const float4 v1 = *reinterpret_cast<const float4*>(&x[row * DCOLS + c * 8 + 4]);
    float ss = v0.x * v0.x + v0.y * v0.y + v0.z * v0.z + v0.w * v0.w
             + v1.x * v1.x + v1.y * v1.y + v1.z * v1.z + v1.w * v1.w;
#pragma unroll
    for (int off = 16; off >= 1; off >>= 1) ss += __shfl_xor(ss, off, 32);
    const float inv = 1.0f / fmaxf(sqrtf(ss), 1e-12f);

    const float f[8] = {v0.x, v0.y, v0.z, v0.w, v1.x, v1.y, v1.z, v1.w};
    unsigned int lo = 0, hi = 0;
#pragma unroll
    for (int i = 0; i < 4; ++i) {
        const unsigned short hb = __half_as_ushort(__float2half(f[i] * inv));
        lo |= (unsigned int)(hb >> 8) << (8 * i);           // e5m2 = fp16 top byte
    }
#pragma unroll
    for (int i = 0; i < 4; ++i) {
        const unsigned short hb = __half_as_ushort(__float2half(f[4 + i] * inv));
        hi |= (unsigned int)(hb >> 8) << (8 * i);
    }
    uint2 o; o.x = lo; o.y = hi;
    *reinterpret_cast<uint2*>(e + (size_t)row * DCOLS + c * 8) = o;
}

// Stage one 128x32 fp8 B panel (4 KB) for K-step kt into a ring slot.
// LDS blob layout: blob[g] (g = 16-row group, 0..7) = 512 B; within a blob,
// 16B chunk cc holds row (cc>>1), k-halves (cc&1): global 16 consecutive fp8.
// Lane (lr,hk) later reads b64 at blob + lr*32 + hk*8 (dense 512B per wave).
// Linear LDS dest = base + chunk*16 (wave-uniform + lane*16, rule #21).
__device__ __forceinline__ void stage_B(const unsigned char* __restrict__ ebase,
                                        char* Bbuf, int kt, int tid) {
    const int g  = tid >> 5;
    const int cc = tid & 31;
    const int go = (g * 16 + (cc >> 1)) * DCOLS + kt * 32 + (cc & 1) * 16;
    __builtin_amdgcn_global_load_lds(
        (const __attribute__((address_space(1))) void*)(ebase + go),
        (__attribute__((address_space(3))) void*)(Bbuf + tid * 16), 16, 0, 0);
}

// --- Kernel 2: persistent run-blocks. Block = (bi, run of <=4 j-tiles).
// A panel (128 x full K=256 fp8, 32 KB) staged ONCE per block; B panels (4 KB
// per BK=32 step) flow through a counted-vmcnt ring-4 across tile boundaries
// (uniform vmcnt(2): wrap-stages keep 3 outstanding; wrapped writes land in
// slots never read again). 4 waves (2x2), wave tile 64x64 = acc[4][4] of
// 16x16x32 bf8_bf8 MFMA. 48 KB LDS + <=128 VGPR -> 3 blocks/CU, all 544
// blocks co-resident (zero serial generations).
__global__ __launch_bounds__(256, 4) void tile_kernel(const unsigned char* __restrict__ e,
                                                      float* __restrict__ part) {
    // XCD-chunked bijective remap (544 = 8*68): same-bi runs cluster per XCD L2.
    const int orig = blockIdx.x;
    int bb = (orig & 7) * 68 + (orig >> 3);
    int bi = 0;
    while (bb >= ((NT - bi) + 3) >> 2) { bb -= ((NT - bi) + 3) >> 2; ++bi; }
    const int j0 = bi + bb * 4;
    const int nj = min(4, NT - j0);
    const int NS = nj * 8;                    // B K-step stream length

    __shared__ char As[32768];                // A: [kt 0..7][g 0..7][512 B]
    __shared__ char Bring[4][4096];           // B ring: [slot][g 0..7][512 B]
    __shared__ float red[4];

    const int t = threadIdx.x;
    const int l = t & 63;
    const int w = t >> 6;       // 0..3
    const int wr = w >> 1;      // wave row 0..1 (64 rows each)
    const int wc = w & 1;       // wave col 0..1 (64 cols each)
    const int lr = l & 15;
    const int hk = l >> 4;
    const int lane_off = lr * 32 + hk * 8;    // b64 read offset within a blob

    const unsigned char* eA = e + (size_t)bi * 128 * DCOLS;

    // --- prologue: stage full-K A (8 chunks/thread) + B steps 0,1,2 ---
#pragma unroll
    for (int i = 0; i < 8; ++i) {
        const int u  = i * 256 + t;           // 0..2047
        const int kt = u >> 8, g = (u >> 5) & 7, cc = u & 31;
        const int go = (g * 16 + (cc >> 1)) * DCOLS + kt * 32 + (cc & 1) * 16;
        __builtin_amdgcn_global_load_lds(
            (const __attribute__((address_space(1))) void*)(eA + go),
            (__attribute__((address_space(3))) void*)(As + u * 16), 16, 0, 0);
    }
    stage_B(e + (size_t)j0 * 128 * DCOLS, Bring[0], 0, t);
    stage_B(e + (size_t)j0 * 128 * DCOLS, Bring[1], 1, t);
    stage_B(e + (size_t)j0 * 128 * DCOLS, Bring[2], 2, t);

    f32x4 acc[4][4];
#pragma unroll
    for (int m = 0; m < 4; ++m)
#pragma unroll
        for (int n = 0; n < 4; ++n)
            acc[m][n] = (f32x4){0.f, 0.f, 0.f, 0.f};

    float local = 0.0f;
    for (int s = 0; s < NS; ++s) {
        const int kt = s & 7;
        const int jt = j0 + (s >> 3);
        // counted wait: 3 B-stages outstanding, oldest (this step's) has landed;
        // at s=0 this also implies the 8 A loads + B0 completed (vmcnt in-order).
        asm volatile("s_waitcnt vmcnt(2)" ::: "memory");
        __builtin_amdgcn_s_barrier();
        // stage step s+3 (wrap keeps the outstanding count uniform; wrapped
        // stages write ring slots that are never read again - safe).
        int s3 = s + 3; if (s3 >= NS) s3 -= NS;
        stage_B(e + (size_t)(j0 + (s3 >> 3)) * 128 * DCOLS, Bring[s3 & 3], s3 & 7, t);

        long af[4], bf[4];
#pragma unroll
        for (int m = 0; m < 4; ++m)
            af[m] = *reinterpret_cast<const long*>(
                As + kt * 4096 + (wr * 4 + m) * 512 + lane_off);
#pragma unroll
        for (int n = 0; n < 4; ++n)
            bf[n] = *reinterpret_cast<const long*>(
                Bring[s & 3] + (wc * 4 + n) * 512 + lane_off);
        __builtin_amdgcn_s_setprio(1);
#pragma unroll
        for (int m = 0; m < 4; ++m)
#pragma unroll
            for (int n = 0; n < 4; ++n)
                acc[m][n] = __builtin_amdgcn_mfma_f32_16x16x32_bf8_bf8(
                    af[m], bf[n], acc[m][n], 0, 0, 0);
        __builtin_amdgcn_s_setprio(0);

        // tile complete -> fused epilogue (overlaps in-flight B stages)
        if (kt == 7) {
            // C/D layout (m89-verified, dtype-independent): col=lane&15,
            // row = (lane>>4)*4 + reg.
            const int gi0 = bi * 128 + wr * 64;
            const int gj0 = jt * 128 + wc * 64;
            if (jt == bi) {
#pragma unroll
                for (int m = 0; m < 4; ++m)
#pragma unroll
                    for (int n = 0; n < 4; ++n) {
#pragma unroll
                        for (int r = 0; r < 4; ++r) {
                            const int gi = gi0 + m * 16 + hk * 4 + r;
                            const int gj = gj0 + n * 16 + lr;
                            const float v = acc[m][n][r] - MARGIN;
                            local += (gi < gj) ? fmaxf(v, 0.0f) : 0.0f;
                        }
                        acc[m][n] = (f32x4){0.f, 0.f, 0.f, 0.f};
                    }
            } else {   // jt > bi: every (gi,gj) is strictly upper-triangular
#pragma unroll
                for (int m = 0; m < 4; ++m)
#pragma unroll
                    for (int n = 0; n < 4; ++n) {
#pragma unroll
                        for (int r = 0; r < 4; ++r)
                            local += fmaxf(acc[m][n][r] - MARGIN, 0.0f);
                        acc[m][n] = (f32x4){0.f, 0.f, 0.f, 0.f};
                    }
            }
        }
    }

    // --- block reduction -> one partial per block, no atomics ---
#pragma unroll
    for (int off = 32; off >= 1; off >>= 1) local += __shfl_down(local, off);
    if (l == 0) red[w] = local;
    __syncthreads();
    if (t == 0) part[orig] = red[0] + red[1] + red[2] + red[3];
}

// --- Kernel 3: reduce NBLOCKS partials, finalize ---
__global__ __launch_bounds__(256) void fin_kernel(const float* __restrict__ part,
                                                  float* __restrict__ out) {
    __shared__ float red[4];
    const int t = threadIdx.x;
    float v = part[t] + part[t + 256] + (t < NBLOCKS - 512 ? part[t + 512] : 0.0f);
#pragma unroll
    for (int off = 32; off >= 1; off >>= 1) v += __shfl_down(v, off);
    if ((t & 63) == 0) red[t >> 6] = v;
    __syncthreads();
    if (t == 0) out[0] = (red[0] + red[1] + red[2] + red[3]) / 33550336.0f;
}

extern "C" void kernel_launch(void* const* d_in, const int* in_sizes, int n_in,
                              void* d_out, int out_size, void* d_ws, size_t ws_size,
                              hipStream_t stream) {
    const float* x = (const float*)d_in[0];
    float* out = (float*)d_out;
    unsigned char* e = (unsigned char*)d_ws;                       // 2 MB fp8
    float* part = (float*)((char*)d_ws + (size_t)NROWS * DCOLS);   // 544 floats

    norm_kernel<<<NROWS / 8, 256, 0, stream>>>(x, e);
    tile_kernel<<<NBLOCKS, 256, 0, stream>>>(e, part);
    fin_kernel<<<1, 256, 0, stream>>>(part, out);
}